// Round 12
// baseline (40.772 us; speedup 1.0000x reference)
//
#include <hip/hip_runtime.h>
#include <hip/hip_bf16.h>
#include <math.h>

// Problem constants
#define BB 2
#define HH 64
#define WW 64
#define DIMC 128
#define NH 4
#define HD 32
#define KS 7
#define DIL 2
#define NPIX (BB * HH * WW)         // 8192 rows
#define SCALE 0.17677669529663687f  // 32^-0.5

typedef short bf16x8 __attribute__((ext_vector_type(8)));
typedef float f32x4  __attribute__((ext_vector_type(4)));

__device__ __forceinline__ short bf16r(float f) {
    union { float f; unsigned u; } x; x.f = f;
    unsigned r = x.u + 0x7FFF + ((x.u >> 16) & 1);  // RNE
    return (short)(r >> 16);
}
__device__ __forceinline__ float uasf(unsigned u) {
    union { unsigned u; float f; } x; x.u = u; return x.f;
}

// ---------------------------------------------------------------------------
// prep_w (R5, known-good): W f32 [128][128] -> Wt bf16 [z][n][k] transposed.
// ---------------------------------------------------------------------------
__global__ __launch_bounds__(256) void prep_w(
    const float* __restrict__ Wq, const float* __restrict__ Wk,
    const float* __restrict__ Wv, const float* __restrict__ Wo,
    short* __restrict__ Wt)
{
    const int z  = blockIdx.x >> 2;
    const int ks = blockIdx.x & 3;
    const float* W = (z == 0) ? Wq : (z == 1) ? Wk : (z == 2) ? Wv : Wo;

    __shared__ short T[32][136];
    const int t = threadIdx.x;
    const float4* Wg = (const float4*)(W + ks * 32 * 128);

    float4 xv[4];
#pragma unroll
    for (int u = 0; u < 4; ++u) xv[u] = Wg[u * 256 + t];
#pragma unroll
    for (int u = 0; u < 4; ++u) {
        const int e = u * 256 + t;
        const int r = e >> 5;
        const int c = (e & 31) * 4;
        short4 s4;
        s4.x = bf16r(xv[u].x); s4.y = bf16r(xv[u].y);
        s4.z = bf16r(xv[u].z); s4.w = bf16r(xv[u].w);
        *(short4*)&T[r][c] = s4;
    }
    __syncthreads();

    const int c = t >> 1;
    const int h = (t & 1) * 16;
    bf16x8 lo, hi;
#pragma unroll
    for (int i = 0; i < 8; ++i) { lo[i] = T[h + i][c]; hi[i] = T[h + 8 + i][c]; }
    short* outp = Wt + z * 16384 + c * 128 + ks * 32 + h;
    *(bf16x8*)(outp)     = lo;
    *(bf16x8*)(outp + 8) = hi;
}

// ---------------------------------------------------------------------------
// qkv_mfma (R5, known-good): Y = (X @ W + b) * scale via mfma 16x16x32 bf16.
// ---------------------------------------------------------------------------
__global__ __launch_bounds__(256) void qkv_mfma(
    const float* __restrict__ q, const float* __restrict__ k,
    const float* __restrict__ v, const short* __restrict__ Wt,
    const float* __restrict__ bq, const float* __restrict__ bk,
    const float* __restrict__ bv,
    float* __restrict__ qh, short* __restrict__ khb, short* __restrict__ vhb)
{
    const int z = blockIdx.y;
    const float* X    = (z == 0) ? q  : (z == 1) ? k  : v;
    const float* bias = (z == 0) ? bq : (z == 1) ? bk : bv;
    const short* Wz   = Wt + z * 16384;

    const int t    = threadIdx.x;
    const int wv   = t >> 6;
    const int lane = t & 63;
    const int lr   = lane & 15;
    const int lg   = lane >> 4;
    const int row0 = blockIdx.x * 32 + (wv & 1) * 16;
    const int col0 = (wv >> 1) * 64;

    bf16x8 bfr[16];
#pragma unroll
    for (int nt = 0; nt < 4; ++nt) {
        const short* wrow = Wz + (col0 + nt * 16 + lr) * 128 + lg * 8;
#pragma unroll
        for (int kk = 0; kk < 4; ++kk)
            bfr[nt * 4 + kk] = *(const bf16x8*)(wrow + kk * 32);
    }

    const float* xrow = X + (size_t)(row0 + lr) * 128 + lg * 8;
    bf16x8 a[4];
#pragma unroll
    for (int kk = 0; kk < 4; ++kk) {
        const float4 x0 = *(const float4*)(xrow + kk * 32);
        const float4 x1 = *(const float4*)(xrow + kk * 32 + 4);
        bf16x8 av;
        av[0] = bf16r(x0.x); av[1] = bf16r(x0.y);
        av[2] = bf16r(x0.z); av[3] = bf16r(x0.w);
        av[4] = bf16r(x1.x); av[5] = bf16r(x1.y);
        av[6] = bf16r(x1.z); av[7] = bf16r(x1.w);
        a[kk] = av;
    }

#pragma unroll
    for (int nt = 0; nt < 4; ++nt) {
        const int col = col0 + nt * 16 + lr;
        f32x4 acc = {0.f, 0.f, 0.f, 0.f};
#pragma unroll
        for (int kk = 0; kk < 4; ++kk)
            acc = __builtin_amdgcn_mfma_f32_16x16x32_bf16(a[kk], bfr[nt * 4 + kk], acc, 0, 0, 0);
        const float bc = bias[col];
        if (z == 0) {
#pragma unroll
            for (int jj = 0; jj < 4; ++jj)
                qh[(size_t)(row0 + lg * 4 + jj) * 128 + col] = (acc[jj] + bc) * SCALE;
        } else {
            short* Yb = (z == 1) ? khb : vhb;
#pragma unroll
            for (int jj = 0; jj < 4; ++jj)
                Yb[(size_t)(row0 + lg * 4 + jj) * 128 + col] = bf16r(acc[jj] + bc);
        }
    }
}

// NATTEN edge-index helper (L=64, K=7, dil=2, ns=3).
__device__ __forceinline__ void natten_idx(int i, int& s, int& p)
{
    if (i < 6) {                 // i - ns*dil < 0
        s = i & 1;
        p = 6 - (i >> 1);
    } else if (i >= 58) {        // i + ns*dil >= L  (L%dil==0 -> b=0 path)
        s = 50 + (i & 1);        // a + i%dil - K*dil
        p = (63 - i) >> 1;
    } else {
        s = i - 6;
        p = 3;
    }
}

// ---------------------------------------------------------------------------
// natten_out v5: R9's online row-grouped softmax, but 8 lanes per (px,head)
// (each lane owns 4 channels, uint2 K/V loads) -> 262144 threads, 2x waves
// vs R9. No extra work, no merge (clean occupancy A/B vs R9).
// 512 blocks x 512 thr (16 px/block); XCD-swizzled work id.
// ---------------------------------------------------------------------------
__global__ __launch_bounds__(512) void natten_out(
    const float* __restrict__ qh, const short* __restrict__ khb,
    const short* __restrict__ vhb, const float* __restrict__ rpb,
    const short* __restrict__ Wt, const float* __restrict__ bo,
    float* __restrict__ out)
{
    __shared__ short attS[16][136];

    const int blk  = blockIdx.x;
    const int work = (blk & 7) * 64 + (blk >> 3);   // bijective (512 = 8*64)
    const int t    = threadIdx.x;

    // ---------------- S2: neighborhood attention (online, 8 lanes/px-head) --
    {
        const int lane8 = t & 7;          // channel quarter (4 ch)
        const int n   = (t >> 3) & 3;     // head
        const int p   = t >> 5;           // 0..15
        const int g   = work * 16 + p;    // < 8192
        const int j   = g & 63;
        const int i   = (g >> 6) & 63;
        const int b   = g >> 12;

        int si, pi0, sj, pj0;
        natten_idx(i, si, pi0);
        natten_idx(j, sj, pj0);

        const int coff = n * 32 + lane8 * 4;
        const size_t pixb = (size_t)(b * 4096 + i * 64 + j);
        const float4 qv = *(const float4*)(qh + pixb * 128 + coff);

        const float* rp = rpb + n * 169;

        float m = -1e30f, l = 0.0f;
        float o0 = 0.f, o1 = 0.f, o2 = 0.f, o3 = 0.f;

#pragma unroll
        for (int ki = 0; ki < 7; ++ki) {
            const int iy = si + 2 * ki;
            const size_t rowbase = ((size_t)(b * 4096 + iy * 64)) * 128 + coff;
            const float* rrow = rp + (pi0 + ki) * 13 + pj0;

            // 7 independent K loads + partial dots
            float d[7];
#pragma unroll
            for (int kj = 0; kj < 7; ++kj) {
                const int ix = sj + 2 * kj;
                const uint2 kv = *(const uint2*)(khb + rowbase + (size_t)ix * 128);
                float dd =      qv.x * uasf(kv.x << 16);
                dd = fmaf(qv.y, uasf(kv.x & 0xFFFF0000u), dd);
                dd = fmaf(qv.z, uasf(kv.y << 16), dd);
                dd = fmaf(qv.w, uasf(kv.y & 0xFFFF0000u), dd);
                d[kj] = dd;
            }
#pragma unroll
            for (int kj = 0; kj < 7; ++kj) d[kj] += __shfl_xor(d[kj], 1);
#pragma unroll
            for (int kj = 0; kj < 7; ++kj) d[kj] += __shfl_xor(d[kj], 2);
#pragma unroll
            for (int kj = 0; kj < 7; ++kj) d[kj] += __shfl_xor(d[kj], 4);
#pragma unroll
            for (int kj = 0; kj < 7; ++kj) d[kj] += rrow[kj];

            // group max (tree) + online rescale
            const float g01 = fmaxf(d[0], d[1]);
            const float g23 = fmaxf(d[2], d[3]);
            const float g45 = fmaxf(d[4], d[5]);
            const float gm  = fmaxf(fmaxf(g01, g23), fmaxf(g45, d[6]));
            const float mn  = fmaxf(m, gm);
            const float corr = __expf(m - mn);
            m = mn;
            l *= corr;
            o0 *= corr; o1 *= corr; o2 *= corr; o3 *= corr;

#pragma unroll
            for (int kj = 0; kj < 7; ++kj) {
                const float pe = __expf(d[kj] - m);
                d[kj] = pe;
                l += pe;
            }

            // 7 independent V loads + PV accumulation
#pragma unroll
            for (int kj = 0; kj < 7; ++kj) {
                const int ix = sj + 2 * kj;
                const uint2 vv = *(const uint2*)(vhb + rowbase + (size_t)ix * 128);
                const float pe = d[kj];
                o0 = fmaf(pe, uasf(vv.x << 16),          o0);
                o1 = fmaf(pe, uasf(vv.x & 0xFFFF0000u),  o1);
                o2 = fmaf(pe, uasf(vv.y << 16),          o2);
                o3 = fmaf(pe, uasf(vv.y & 0xFFFF0000u),  o3);
            }
        }

        const float inv = 1.0f / l;
        short4 ow;
        ow.x = bf16r(o0 * inv);
        ow.y = bf16r(o1 * inv);
        ow.z = bf16r(o2 * inv);
        ow.w = bf16r(o3 * inv);
        *(short4*)&attS[p][coff] = ow;
    }

    __syncthreads();

    // ---------------- S3: out projection from LDS att tile (8 waves) --------
    {
        const int wv   = t >> 6;          // 0..7
        const int lane = t & 63;
        const int lr   = lane & 15;
        const int lg   = lane >> 4;
        const int col0 = wv * 16;
        const short* Wz = Wt + 3 * 16384;

        bf16x8 bfr[4];
        const short* wrow = Wz + (col0 + lr) * 128 + lg * 8;
#pragma unroll
        for (int kk = 0; kk < 4; ++kk)
            bfr[kk] = *(const bf16x8*)(wrow + kk * 32);

        bf16x8 a[4];
#pragma unroll
        for (int kk = 0; kk < 4; ++kk)
            a[kk] = *(const bf16x8*)&attS[lr][kk * 32 + lg * 8];

        f32x4 acc = {0.f, 0.f, 0.f, 0.f};
#pragma unroll
        for (int kk = 0; kk < 4; ++kk)
            acc = __builtin_amdgcn_mfma_f32_16x16x32_bf16(a[kk], bfr[kk], acc, 0, 0, 0);

        const int col = col0 + lr;
        const float bc = bo[col];
#pragma unroll
        for (int jj = 0; jj < 4; ++jj)
            out[(size_t)(work * 16 + lg * 4 + jj) * 128 + col] = acc[jj] + bc;
    }
}

// ---------------------------------------------------------------------------
extern "C" void kernel_launch(void* const* d_in, const int* in_sizes, int n_in,
                              void* d_out, int out_size, void* d_ws, size_t ws_size,
                              hipStream_t stream)
{
    const float* q   = (const float*)d_in[0];
    const float* k   = (const float*)d_in[1];
    const float* v   = (const float*)d_in[2];
    const float* Wq  = (const float*)d_in[3];
    const float* bq  = (const float*)d_in[4];
    const float* Wk  = (const float*)d_in[5];
    const float* bk  = (const float*)d_in[6];
    const float* Wv  = (const float*)d_in[7];
    const float* bv  = (const float*)d_in[8];
    const float* rpb = (const float*)d_in[9];
    const float* Wo  = (const float*)d_in[10];
    const float* bo  = (const float*)d_in[11];

    float* ws   = (float*)d_ws;
    float* qh   = ws;                                   // f32 [8192][128]  (4 MB)
    short* khb  = (short*)(ws + (size_t)NPIX * 128);    // bf16 [8192][128] (2 MB)
    short* vhb  = khb + (size_t)NPIX * 128;             // bf16 (2 MB)
    short* Wt   = vhb + (size_t)NPIX * 128;             // bf16 [4][128][128] (128 KB)
    float* out  = (float*)d_out;

    hipLaunchKernelGGL(prep_w, dim3(16), dim3(256), 0, stream, Wq, Wk, Wv, Wo, Wt);

    hipLaunchKernelGGL(qkv_mfma, dim3(256, 3), dim3(256), 0, stream,
                       q, k, v, Wt, bq, bk, bv, qh, khb, vhb);

    hipLaunchKernelGGL(natten_out, dim3(512), dim3(512), 0, stream,
                       qh, khb, vhb, rpb, Wt, bo, out);
}

// Round 13
// 38.610 us; speedup vs baseline: 1.0560x; 1.0560x over previous
//
#include <hip/hip_runtime.h>
#include <hip/hip_bf16.h>
#include <math.h>

// Problem constants
#define BB 2
#define HH 64
#define WW 64
#define DIMC 128
#define NH 4
#define HD 32
#define KS 7
#define DIL 2
#define NPIX (BB * HH * WW)         // 8192 rows
#define SCALE 0.17677669529663687f  // 32^-0.5

typedef short bf16x8 __attribute__((ext_vector_type(8)));
typedef float f32x4  __attribute__((ext_vector_type(4)));

__device__ __forceinline__ short bf16r(float f) {
    union { float f; unsigned u; } x; x.f = f;
    unsigned r = x.u + 0x7FFF + ((x.u >> 16) & 1);  // RNE
    return (short)(r >> 16);
}
__device__ __forceinline__ float uasf(unsigned u) {
    union { unsigned u; float f; } x; x.u = u; return x.f;
}

// ---------------------------------------------------------------------------
// prep_w (R5, known-good): W f32 [128][128] -> Wt bf16 [z][n][k] transposed.
// ---------------------------------------------------------------------------
__global__ __launch_bounds__(256) void prep_w(
    const float* __restrict__ Wq, const float* __restrict__ Wk,
    const float* __restrict__ Wv, const float* __restrict__ Wo,
    short* __restrict__ Wt)
{
    const int z  = blockIdx.x >> 2;
    const int ks = blockIdx.x & 3;
    const float* W = (z == 0) ? Wq : (z == 1) ? Wk : (z == 2) ? Wv : Wo;

    __shared__ short T[32][136];
    const int t = threadIdx.x;
    const float4* Wg = (const float4*)(W + ks * 32 * 128);

    float4 xv[4];
#pragma unroll
    for (int u = 0; u < 4; ++u) xv[u] = Wg[u * 256 + t];
#pragma unroll
    for (int u = 0; u < 4; ++u) {
        const int e = u * 256 + t;
        const int r = e >> 5;
        const int c = (e & 31) * 4;
        short4 s4;
        s4.x = bf16r(xv[u].x); s4.y = bf16r(xv[u].y);
        s4.z = bf16r(xv[u].z); s4.w = bf16r(xv[u].w);
        *(short4*)&T[r][c] = s4;
    }
    __syncthreads();

    const int c = t >> 1;
    const int h = (t & 1) * 16;
    bf16x8 lo, hi;
#pragma unroll
    for (int i = 0; i < 8; ++i) { lo[i] = T[h + i][c]; hi[i] = T[h + 8 + i][c]; }
    short* outp = Wt + z * 16384 + c * 128 + ks * 32 + h;
    *(bf16x8*)(outp)     = lo;
    *(bf16x8*)(outp + 8) = hi;
}

// ---------------------------------------------------------------------------
// qkv_mfma (R5, known-good): Y = (X @ W + b) * scale via mfma 16x16x32 bf16.
// ---------------------------------------------------------------------------
__global__ __launch_bounds__(256) void qkv_mfma(
    const float* __restrict__ q, const float* __restrict__ k,
    const float* __restrict__ v, const short* __restrict__ Wt,
    const float* __restrict__ bq, const float* __restrict__ bk,
    const float* __restrict__ bv,
    float* __restrict__ qh, short* __restrict__ khb, short* __restrict__ vhb)
{
    const int z = blockIdx.y;
    const float* X    = (z == 0) ? q  : (z == 1) ? k  : v;
    const float* bias = (z == 0) ? bq : (z == 1) ? bk : bv;
    const short* Wz   = Wt + z * 16384;

    const int t    = threadIdx.x;
    const int wv   = t >> 6;
    const int lane = t & 63;
    const int lr   = lane & 15;
    const int lg   = lane >> 4;
    const int row0 = blockIdx.x * 32 + (wv & 1) * 16;
    const int col0 = (wv >> 1) * 64;

    bf16x8 bfr[16];
#pragma unroll
    for (int nt = 0; nt < 4; ++nt) {
        const short* wrow = Wz + (col0 + nt * 16 + lr) * 128 + lg * 8;
#pragma unroll
        for (int kk = 0; kk < 4; ++kk)
            bfr[nt * 4 + kk] = *(const bf16x8*)(wrow + kk * 32);
    }

    const float* xrow = X + (size_t)(row0 + lr) * 128 + lg * 8;
    bf16x8 a[4];
#pragma unroll
    for (int kk = 0; kk < 4; ++kk) {
        const float4 x0 = *(const float4*)(xrow + kk * 32);
        const float4 x1 = *(const float4*)(xrow + kk * 32 + 4);
        bf16x8 av;
        av[0] = bf16r(x0.x); av[1] = bf16r(x0.y);
        av[2] = bf16r(x0.z); av[3] = bf16r(x0.w);
        av[4] = bf16r(x1.x); av[5] = bf16r(x1.y);
        av[6] = bf16r(x1.z); av[7] = bf16r(x1.w);
        a[kk] = av;
    }

#pragma unroll
    for (int nt = 0; nt < 4; ++nt) {
        const int col = col0 + nt * 16 + lr;
        f32x4 acc = {0.f, 0.f, 0.f, 0.f};
#pragma unroll
        for (int kk = 0; kk < 4; ++kk)
            acc = __builtin_amdgcn_mfma_f32_16x16x32_bf16(a[kk], bfr[nt * 4 + kk], acc, 0, 0, 0);
        const float bc = bias[col];
        if (z == 0) {
#pragma unroll
            for (int jj = 0; jj < 4; ++jj)
                qh[(size_t)(row0 + lg * 4 + jj) * 128 + col] = (acc[jj] + bc) * SCALE;
        } else {
            short* Yb = (z == 1) ? khb : vhb;
#pragma unroll
            for (int jj = 0; jj < 4; ++jj)
                Yb[(size_t)(row0 + lg * 4 + jj) * 128 + col] = bf16r(acc[jj] + bc);
        }
    }
}

// NATTEN edge-index helper (L=64, K=7, dil=2, ns=3).
__device__ __forceinline__ void natten_idx(int i, int& s, int& p)
{
    if (i < 6) {                 // i - ns*dil < 0
        s = i & 1;
        p = 6 - (i >> 1);
    } else if (i >= 58) {        // i + ns*dil >= L  (L%dil==0 -> b=0 path)
        s = 50 + (i & 1);        // a + i%dil - K*dil
        p = (63 - i) >> 1;
    } else {
        s = i - 6;
        p = 3;
    }
}

// ---------------------------------------------------------------------------
// natten_out v6: R9's online softmax + LDS-staged K tile.
// Block = 16 px of one image row: K working set = 7 dilated rows x 28-col
// halo union, staged coalesced into LDS [7][28][136] (53KB, padded rows).
// K-dot reads become ds_read_b128; V stays global (latency-tolerant).
// attS reuses the K-tile LDS (dead after S2). 512 blocks x 256 thr.
// ---------------------------------------------------------------------------
__global__ __launch_bounds__(256) void natten_out(
    const float* __restrict__ qh, const short* __restrict__ khb,
    const short* __restrict__ vhb, const float* __restrict__ rpb,
    const short* __restrict__ Wt, const float* __restrict__ bo,
    float* __restrict__ out)
{
    __shared__ short smem[7 * 28 * 136];          // 53,312 B K tile
    short (*kls)[28][136] = (short (*)[28][136])smem;
    short (*attS)[136]    = (short (*)[136])smem; // union: reused for att tile

    const int blk  = blockIdx.x;
    const int work = (blk & 7) * 64 + (blk >> 3);   // bijective (512 = 8*64)
    const int t    = threadIdx.x;

    // Block geometry: 16 px = one (b, i, j0..j0+15) row segment.
    const int j0 = (work & 3) * 16;
    const int i_ = (work >> 2) & 63;
    const int b_ = work >> 8;

    int si_, pi_, sj0, pj_;
    natten_idx(i_, si_, pi_);
    natten_idx(j0, sj0, pj_);        // colbase = sj(j0)
    const int colbase = sj0;

    // ---------------- Stage K tile: 7 rows x 28 cols x 128 ch ---------------
    {
        const size_t bbase = (size_t)(b_ * 4096) * 128;
#pragma unroll
        for (int u = t; u < 3136; u += 256) {       // 3136 = 196 rows * 16 chunks
            const int row  = u >> 4;                // 0..195
            const int ch16 = (u & 15) * 8;          // short offset of 16B chunk
            const int ki   = row / 28;
            const int c    = row - ki * 28;
            int col = colbase + c;
            col = (col > 63) ? 63 : col;            // clamp (unused slots)
            const int iy = si_ + 2 * ki;
            const uint4 kv = *(const uint4*)(khb + bbase + (size_t)(iy * 64 + col) * 128 + ch16);
            *(uint4*)&kls[ki][c][ch16] = kv;
        }
    }
    __syncthreads();

    float o0, o1, o2, o3, o4, o5, o6, o7, invl;
    int p_, coff_;

    // ---------------- S2: attention (K from LDS, V global) ------------------
    {
        const int lane4 = t & 3;
        const int n   = (t >> 2) & 3;
        const int p   = t >> 4;            // 0..15
        const int j   = j0 + p;

        int si, pi0, sj, pj0;
        natten_idx(i_, si, pi0);
        natten_idx(j, sj, pj0);

        const int coff = n * 32 + lane4 * 8;
        const size_t pixb = (size_t)(b_ * 4096 + i_ * 64 + j);
        const float4 q0 = *(const float4*)(qh + pixb * 128 + coff);
        const float4 q1 = *(const float4*)(qh + pixb * 128 + coff + 4);

        const float* rp = rpb + n * 169;
        const int cj0 = sj - colbase;      // col offset of kj=0 (0..27-12)

        float m = -1e30f, l = 0.0f;
        float o[8] = {0.f, 0.f, 0.f, 0.f, 0.f, 0.f, 0.f, 0.f};

#pragma unroll
        for (int ki = 0; ki < 7; ++ki) {
            const int iy = si + 2 * ki;
            const size_t rowbase = ((size_t)(b_ * 4096 + iy * 64)) * 128 + coff;
            const float* rrow = rp + (pi0 + ki) * 13 + pj0;

            // 7 K dots from LDS
            float d[7];
#pragma unroll
            for (int kj = 0; kj < 7; ++kj) {
                const uint4 kv = *(const uint4*)&kls[ki][cj0 + 2 * kj][coff];
                float dd =      q0.x * uasf(kv.x << 16);
                dd = fmaf(q0.y, uasf(kv.x & 0xFFFF0000u), dd);
                dd = fmaf(q0.z, uasf(kv.y << 16), dd);
                dd = fmaf(q0.w, uasf(kv.y & 0xFFFF0000u), dd);
                dd = fmaf(q1.x, uasf(kv.z << 16), dd);
                dd = fmaf(q1.y, uasf(kv.z & 0xFFFF0000u), dd);
                dd = fmaf(q1.z, uasf(kv.w << 16), dd);
                dd = fmaf(q1.w, uasf(kv.w & 0xFFFF0000u), dd);
                d[kj] = dd;
            }
#pragma unroll
            for (int kj = 0; kj < 7; ++kj) d[kj] += __shfl_xor(d[kj], 1);
#pragma unroll
            for (int kj = 0; kj < 7; ++kj) d[kj] += __shfl_xor(d[kj], 2);
#pragma unroll
            for (int kj = 0; kj < 7; ++kj) d[kj] += rrow[kj];

            // group max (tree) + online rescale
            const float g01 = fmaxf(d[0], d[1]);
            const float g23 = fmaxf(d[2], d[3]);
            const float g45 = fmaxf(d[4], d[5]);
            const float gm  = fmaxf(fmaxf(g01, g23), fmaxf(g45, d[6]));
            const float mn  = fmaxf(m, gm);
            const float corr = __expf(m - mn);
            m = mn;
            l *= corr;
#pragma unroll
            for (int e = 0; e < 8; ++e) o[e] *= corr;

#pragma unroll
            for (int kj = 0; kj < 7; ++kj) {
                const float pe = __expf(d[kj] - m);
                d[kj] = pe;
                l += pe;
            }

            // 7 independent V loads (global) + PV accumulation
#pragma unroll
            for (int kj = 0; kj < 7; ++kj) {
                const int ix = sj + 2 * kj;
                const uint4 vv = *(const uint4*)(vhb + rowbase + (size_t)ix * 128);
                const float pe = d[kj];
                o[0] = fmaf(pe, uasf(vv.x << 16),          o[0]);
                o[1] = fmaf(pe, uasf(vv.x & 0xFFFF0000u),  o[1]);
                o[2] = fmaf(pe, uasf(vv.y << 16),          o[2]);
                o[3] = fmaf(pe, uasf(vv.y & 0xFFFF0000u),  o[3]);
                o[4] = fmaf(pe, uasf(vv.z << 16),          o[4]);
                o[5] = fmaf(pe, uasf(vv.z & 0xFFFF0000u),  o[5]);
                o[6] = fmaf(pe, uasf(vv.w << 16),          o[6]);
                o[7] = fmaf(pe, uasf(vv.w & 0xFFFF0000u),  o[7]);
            }
        }

        invl = 1.0f / l;
        o0 = o[0]; o1 = o[1]; o2 = o[2]; o3 = o[3];
        o4 = o[4]; o5 = o[5]; o6 = o[6]; o7 = o[7];
        p_ = p; coff_ = coff;
    }

    __syncthreads();   // all K-tile reads done; safe to overwrite with attS

    {
        bf16x8 ow;
        ow[0] = bf16r(o0 * invl); ow[1] = bf16r(o1 * invl);
        ow[2] = bf16r(o2 * invl); ow[3] = bf16r(o3 * invl);
        ow[4] = bf16r(o4 * invl); ow[5] = bf16r(o5 * invl);
        ow[6] = bf16r(o6 * invl); ow[7] = bf16r(o7 * invl);
        *(bf16x8*)&attS[p_][coff_] = ow;
    }

    __syncthreads();

    // ---------------- S3: out projection from LDS att tile (4 waves) --------
    {
        const int wv   = t >> 6;
        const int lane = t & 63;
        const int lr   = lane & 15;
        const int lg   = lane >> 4;
        const int col0 = wv * 32;
        const short* Wz = Wt + 3 * 16384;

        bf16x8 bfr[8];
#pragma unroll
        for (int nt = 0; nt < 2; ++nt) {
            const short* wrow = Wz + (col0 + nt * 16 + lr) * 128 + lg * 8;
#pragma unroll
            for (int kk = 0; kk < 4; ++kk)
                bfr[nt * 4 + kk] = *(const bf16x8*)(wrow + kk * 32);
        }
        bf16x8 a[4];
#pragma unroll
        for (int kk = 0; kk < 4; ++kk)
            a[kk] = *(const bf16x8*)&attS[lr][kk * 32 + lg * 8];

#pragma unroll
        for (int nt = 0; nt < 2; ++nt) {
            const int col = col0 + nt * 16 + lr;
            f32x4 acc = {0.f, 0.f, 0.f, 0.f};
#pragma unroll
            for (int kk = 0; kk < 4; ++kk)
                acc = __builtin_amdgcn_mfma_f32_16x16x32_bf16(a[kk], bfr[nt * 4 + kk], acc, 0, 0, 0);
            const float bc = bo[col];
#pragma unroll
            for (int jj = 0; jj < 4; ++jj)
                out[(size_t)(work * 16 + lg * 4 + jj) * 128 + col] = acc[jj] + bc;
        }
    }
}

// ---------------------------------------------------------------------------
extern "C" void kernel_launch(void* const* d_in, const int* in_sizes, int n_in,
                              void* d_out, int out_size, void* d_ws, size_t ws_size,
                              hipStream_t stream)
{
    const float* q   = (const float*)d_in[0];
    const float* k   = (const float*)d_in[1];
    const float* v   = (const float*)d_in[2];
    const float* Wq  = (const float*)d_in[3];
    const float* bq  = (const float*)d_in[4];
    const float* Wk  = (const float*)d_in[5];
    const float* bk  = (const float*)d_in[6];
    const float* Wv  = (const float*)d_in[7];
    const float* bv  = (const float*)d_in[8];
    const float* rpb = (const float*)d_in[9];
    const float* Wo  = (const float*)d_in[10];
    const float* bo  = (const float*)d_in[11];

    float* ws   = (float*)d_ws;
    float* qh   = ws;                                   // f32 [8192][128]  (4 MB)
    short* khb  = (short*)(ws + (size_t)NPIX * 128);    // bf16 [8192][128] (2 MB)
    short* vhb  = khb + (size_t)NPIX * 128;             // bf16 (2 MB)
    short* Wt   = vhb + (size_t)NPIX * 128;             // bf16 [4][128][128] (128 KB)
    float* out  = (float*)d_out;

    hipLaunchKernelGGL(prep_w, dim3(16), dim3(256), 0, stream, Wq, Wk, Wv, Wo, Wt);

    hipLaunchKernelGGL(qkv_mfma, dim3(256, 3), dim3(256), 0, stream,
                       q, k, v, Wt, bq, bk, bv, qh, khb, vhb);

    hipLaunchKernelGGL(natten_out, dim3(512), dim3(256), 0, stream,
                       qh, khb, vhb, rpb, Wt, bo, out);
}